// Round 2
// baseline (291.750 us; speedup 1.0000x reference)
//
#include <hip/hip_runtime.h>
#include <hip/hip_bf16.h>
#include <math.h>

#define BB 2
#define SS 2048
#define HH 16
#define DH 64
#define DQK 128
#define DD (HH*DH)

typedef _Float16 half8_t __attribute__((ext_vector_type(8)));
typedef float f32x4_t __attribute__((ext_vector_type(4)));

// LUT-equivalent sin/cos: explicit fract in revolution space (matches reference's
// (theta/2pi % 1) structure; v_sin input must be range-reduced for |theta|~3300).
__device__ __forceinline__ void fsincos(float th, float* sn, float* cs) {
  float rev = th * 0.15915494309189535f;
  rev -= floorf(rev);
  float ang = rev * 6.283185307179586f;
  *sn = __sinf(ang);
  *cs = __cosf(ang);
}

__global__ __launch_bounds__(256) void gen_qkv(
    const float* __restrict__ x,
    const float* __restrict__ wq, const float* __restrict__ bq,
    const float* __restrict__ phq,
    const float* __restrict__ wk, const float* __restrict__ bk,
    const float* __restrict__ phk,
    const float* __restrict__ wv, const float* __restrict__ bv,
    _Float16* __restrict__ Qd, _Float16* __restrict__ Kd, _Float16* __restrict__ Vtd)
{
  int e = blockIdx.x * 256 + threadIdx.x;          // over B*S*H*DH = 2^22
  int d = e & (DH - 1);
  int h = (e >> 6) & (HH - 1);
  int s = (e >> 10) & (SS - 1);
  int b = e >> 21;
  int hd = h * DH + d;
  float xv = x[e];
  float t = (float)s;
  size_t bh = (size_t)b * HH + h;
  {
    float th = xv / (1.f + fabsf(wq[hd])) + bq[hd] + t * phq[hd];
    float sn, cs; fsincos(th, &sn, &cs);
    size_t base = (bh * SS + s) * DQK;
    Qd[base + d]      = (_Float16)cs;
    Qd[base + DH + d] = (_Float16)sn;
  }
  {
    float th = xv / (1.f + fabsf(wk[hd])) + bk[hd] + t * phk[hd];
    float sn, cs; fsincos(th, &sn, &cs);
    size_t base = (bh * SS + s) * DQK;
    Kd[base + d]      = (_Float16)cs;
    Kd[base + DH + d] = (_Float16)sn;
  }
  {
    float th = xv / (1.f + fabsf(wv[hd])) + bv[hd];
    float sn, cs; fsincos(th, &sn, &cs);
    Vtd[(bh * DH + d) * SS + s] = (_Float16)(cs + sn);  // transposed: [bh][dv][s]
  }
}

// One block = 4 waves = 64 Q rows. Wave w owns rows q0B+16w..+15.
// K chunk (32 keys x 128) + V chunk (64 dv x 32 keys) staged in LDS per block.
__global__ __launch_bounds__(256) void flash_attn(
    const _Float16* __restrict__ Qd, const _Float16* __restrict__ Kd,
    const _Float16* __restrict__ Vtd,
    const float* __restrict__ wout, const float* __restrict__ bout,
    float* __restrict__ out)
{
  int qb = blockIdx.x & 31;          // 32 q-blocks of 64 rows
  int bh = blockIdx.x >> 5;          // b*16+h
  int q0B = qb * 64;
  int wave = threadIdx.x >> 6;
  int lane = threadIdx.x & 63;
  int lm = lane & 15, lq = lane >> 4;
  int q0 = q0B + wave * 16;

  __shared__ __align__(16) _Float16 Kl[32 * 136];     // +8 f16 row pad (bank conflicts)
  __shared__ __align__(16) _Float16 Vl[64 * 40];      // [dv][key], +8 pad
  __shared__ __align__(16) _Float16 Pl[4][16 * 40];   // per-wave P buffer, +8 pad

  // Q A-frags resident: A[m=lm][k=c*32+lq*8+j]
  const _Float16* Qb = Qd + ((size_t)bh * SS + q0) * DQK;
  half8_t aq[4];
#pragma unroll
  for (int c = 0; c < 4; c++)
    aq[c] = *(const half8_t*)(Qb + lm * DQK + c * 32 + lq * 8);

  f32x4_t o[4];
#pragma unroll
  for (int nt = 0; nt < 4; nt++) o[nt] = (f32x4_t){0.f, 0.f, 0.f, 0.f};
  float m_i[4], l_i[4];
#pragma unroll
  for (int r = 0; r < 4; r++) { m_i[r] = -1e30f; l_i[r] = 0.f; }

  const _Float16* Kb = Kd + (size_t)bh * SS * DQK;
  const _Float16* Vb = Vtd + (size_t)bh * DH * SS;
  const float scale = 0.08838834764831845f;  // 1/sqrt(128)

  int nch = q0B / 32 + 2;
  for (int kt = 0; kt < nch; ++kt) {
    int k0 = kt * 32;
    __syncthreads();
    // stage K chunk: 512 x 16B segments, 2 per thread
#pragma unroll
    for (int i = 0; i < 2; i++) {
      int seg = threadIdx.x + i * 256;
      int key = seg >> 4;
      int fo = (seg & 15) * 8;
      *(half8_t*)(&Kl[key * 136 + fo]) =
          *(const half8_t*)(Kb + (size_t)(k0 + key) * DQK + fo);
    }
    {  // stage V chunk: 256 x 16B segments
      int dv = threadIdx.x >> 2;
      int ko = (threadIdx.x & 3) * 8;
      *(half8_t*)(&Vl[dv * 40 + ko]) =
          *(const half8_t*)(Vb + (size_t)dv * SS + k0 + ko);
    }
    __syncthreads();

    // S = Q K^T : two 16x16 tiles (keys k0..+15, k0+16..+31)
    f32x4_t c0 = (f32x4_t){0.f, 0.f, 0.f, 0.f};
    f32x4_t c1 = (f32x4_t){0.f, 0.f, 0.f, 0.f};
#pragma unroll
    for (int c = 0; c < 4; c++) {
      half8_t b0 = *(const half8_t*)(&Kl[lm * 136 + c * 32 + lq * 8]);
      half8_t b1 = *(const half8_t*)(&Kl[(lm + 16) * 136 + c * 32 + lq * 8]);
      c0 = __builtin_amdgcn_mfma_f32_16x16x32_f16(aq[c], b0, c0, 0, 0, 0);
      c1 = __builtin_amdgcn_mfma_f32_16x16x32_f16(aq[c], b1, c1, 0, 0, 0);
    }

    // online softmax; C layout: row = lq*4+r (q), col = lm (key)
    bool maskit = (kt >= nch - 2);
    float s0[4], s1[4];
#pragma unroll
    for (int r = 0; r < 4; r++) {
      s0[r] = c0[r] * scale;
      s1[r] = c1[r] * scale;
      if (maskit) {
        int qrow = q0 + lq * 4 + r;
        if (k0 + lm > qrow)      s0[r] = -1e30f;
        if (k0 + 16 + lm > qrow) s1[r] = -1e30f;
      }
    }
    float mx[4];
#pragma unroll
    for (int r = 0; r < 4; r++) mx[r] = fmaxf(s0[r], s1[r]);
#pragma unroll
    for (int off = 1; off < 16; off <<= 1) {
#pragma unroll
      for (int r = 0; r < 4; r++)
        mx[r] = fmaxf(mx[r], __shfl_xor(mx[r], off, 64));
    }
    float al[4], ps[4];
#pragma unroll
    for (int r = 0; r < 4; r++) {
      float mn = fmaxf(m_i[r], mx[r]);
      al[r] = __expf(m_i[r] - mn);
      m_i[r] = mn;
      s0[r] = __expf(s0[r] - mn);
      s1[r] = __expf(s1[r] - mn);
      ps[r] = s0[r] + s1[r];
    }
#pragma unroll
    for (int off = 1; off < 16; off <<= 1) {
#pragma unroll
      for (int r = 0; r < 4; r++)
        ps[r] += __shfl_xor(ps[r], off, 64);
    }
#pragma unroll
    for (int r = 0; r < 4; r++) l_i[r] = l_i[r] * al[r] + ps[r];
#pragma unroll
    for (int nt = 0; nt < 4; nt++)
#pragma unroll
      for (int r = 0; r < 4; r++) o[nt][r] *= al[r];

    // P: C-layout -> A-layout via per-wave LDS round trip (m120 pattern)
    _Float16* pw = &Pl[wave][0];
#pragma unroll
    for (int r = 0; r < 4; r++) {
      pw[(lq * 4 + r) * 40 + lm]      = (_Float16)s0[r];
      pw[(lq * 4 + r) * 40 + 16 + lm] = (_Float16)s1[r];
    }
    half8_t pa = *(const half8_t*)(&pw[lm * 40 + lq * 8]);

    // O += P V : 4 n-tiles of 16 over dv=64
#pragma unroll
    for (int nt = 0; nt < 4; nt++) {
      half8_t bv2 = *(const half8_t*)(&Vl[(nt * 16 + lm) * 40 + lq * 8]);
      o[nt] = __builtin_amdgcn_mfma_f32_16x16x32_f16(pa, bv2, o[nt], 0, 0, 0);
    }
  }

  // fused epilogue: y = cos+sin( o/l / (1+|w_out|) + b_out ), fp32 out
  int b = bh >> 4, h = bh & 15;
#pragma unroll
  for (int r = 0; r < 4; r++) {
    float rl = 1.f / l_i[r];
    int qrow = q0 + lq * 4 + r;
#pragma unroll
    for (int nt = 0; nt < 4; nt++) {
      int dcol = h * DH + nt * 16 + lm;
      float ov = o[nt][r] * rl;
      float th = ov / (1.f + fabsf(wout[dcol])) + bout[dcol];
      float sn, cs; fsincos(th, &sn, &cs);
      out[((size_t)b * SS + qrow) * DD + dcol] = cs + sn;
    }
  }
}

extern "C" void kernel_launch(void* const* d_in, const int* in_sizes, int n_in,
                              void* d_out, int out_size, void* d_ws, size_t ws_size,
                              hipStream_t stream) {
  (void)in_sizes; (void)n_in; (void)out_size; (void)ws_size;
  const float* x   = (const float*)d_in[0];
  const float* wq  = (const float*)d_in[1];
  const float* bq  = (const float*)d_in[2];
  const float* phq = (const float*)d_in[3];
  const float* wk  = (const float*)d_in[4];
  const float* bk  = (const float*)d_in[5];
  const float* phk = (const float*)d_in[6];
  const float* wv  = (const float*)d_in[7];
  const float* bv  = (const float*)d_in[8];
  const float* wo  = (const float*)d_in[9];
  const float* bo  = (const float*)d_in[10];

  _Float16* Qd  = (_Float16*)d_ws;
  _Float16* Kd  = Qd + (size_t)BB * HH * SS * DQK;
  _Float16* Vtd = Kd + (size_t)BB * HH * SS * DQK;

  gen_qkv<<<(BB * SS * HH * DH) / 256, 256, 0, stream>>>(
      x, wq, bq, phq, wk, bk, phk, wv, bv, Qd, Kd, Vtd);
  flash_attn<<<BB * HH * (SS / 64), 256, 0, stream>>>(
      Qd, Kd, Vtd, wo, bo, (float*)d_out);
}

// Round 3
// 163.850 us; speedup vs baseline: 1.7806x; 1.7806x over previous
//
#include <hip/hip_runtime.h>
#include <hip/hip_bf16.h>
#include <math.h>

#define BB 2
#define SS 2048
#define HH 16
#define DH 64
#define DQK 128
#define DD (HH*DH)
#define QSCALE 0.08838834764831845f   // 1/sqrt(128), folded into Q at gen

typedef _Float16 half8_t __attribute__((ext_vector_type(8)));
typedef float f32x4_t __attribute__((ext_vector_type(4)));
typedef float f32x4v __attribute__((ext_vector_type(4)));

__device__ __forceinline__ void fsincos(float th, float* sn, float* cs) {
  float rev = th * 0.15915494309189535f;
  rev -= floorf(rev);
  float ang = rev * 6.283185307179586f;
  *sn = __sinf(ang);
  *cs = __cosf(ang);
}

// Block per (bh, s-tile of 64). 256 thr: t>>2 = local s row, (t&3)*16 = d quad.
// V transposed via LDS so the global V^T write is 128B-coalesced rows.
__global__ __launch_bounds__(256) void gen_qkv(
    const float* __restrict__ x,
    const float* __restrict__ wq, const float* __restrict__ bq,
    const float* __restrict__ phq,
    const float* __restrict__ wk, const float* __restrict__ bk,
    const float* __restrict__ phk,
    const float* __restrict__ wv, const float* __restrict__ bv,
    _Float16* __restrict__ Qd, _Float16* __restrict__ Kd, _Float16* __restrict__ Vtd)
{
  int stile = blockIdx.x & 31;
  int bh    = blockIdx.x >> 5;
  int b = bh >> 4, h = bh & 15;
  int t = threadIdx.x;
  int sl = t >> 2;                 // 0..63
  int dq = (t & 3) << 4;           // 0,16,32,48
  int s  = stile * 64 + sl;

  __shared__ _Float16 Vl[64 * 65]; // pitch 65: odd -> conflict-light transpose

  const float* xr = x + (((size_t)b * SS + s) * HH + h) * DH + dq;
  float xv[16];
#pragma unroll
  for (int i = 0; i < 4; i++)
    *(f32x4v*)(&xv[i * 4]) = *(const f32x4v*)(xr + i * 4);

  float tv = (float)s;
  _Float16 qc[16], qs[16], kc[16], ks[16];
#pragma unroll
  for (int i = 0; i < 16; i++) {
    int d = dq + i;
    int hd = h * DH + d;
    {
      float th = xv[i] / (1.f + fabsf(wq[hd])) + bq[hd] + tv * phq[hd];
      float sn, cs; fsincos(th, &sn, &cs);
      qc[i] = (_Float16)(cs * QSCALE);
      qs[i] = (_Float16)(sn * QSCALE);
    }
    {
      float th = xv[i] / (1.f + fabsf(wk[hd])) + bk[hd] + tv * phk[hd];
      float sn, cs; fsincos(th, &sn, &cs);
      kc[i] = (_Float16)cs;
      ks[i] = (_Float16)sn;
    }
    {
      float th = xv[i] / (1.f + fabsf(wv[hd])) + bv[hd];
      float sn, cs; fsincos(th, &sn, &cs);
      Vl[d * 65 + sl] = (_Float16)(cs + sn);
    }
  }
  size_t qbase = ((size_t)bh * SS + s) * DQK;
#pragma unroll
  for (int i = 0; i < 2; i++) {
    *(half8_t*)(Qd + qbase + dq + i * 8)      = *(half8_t*)(&qc[i * 8]);
    *(half8_t*)(Qd + qbase + DH + dq + i * 8) = *(half8_t*)(&qs[i * 8]);
    *(half8_t*)(Kd + qbase + dq + i * 8)      = *(half8_t*)(&kc[i * 8]);
    *(half8_t*)(Kd + qbase + DH + dq + i * 8) = *(half8_t*)(&ks[i * 8]);
  }
  __syncthreads();
  // write V^T rows: 64 consecutive f16 per (d) row -> 128B coalesced
#pragma unroll
  for (int i = 0; i < 16; i++) {
    int dout = i * 4 + (t >> 6);
    Vtd[((size_t)bh * DH + dout) * SS + stile * 64 + (t & 63)] =
        Vl[dout * 65 + (t & 63)];
  }
}

// 512 blocks = 32 bh x 16 pairs. Block j does q-tile (31-j) then (j): 33
// uniform 64-key chunks. 8 waves: g=wave>>1 row-group (16 rows), h=wave&1
// key-half (32 keys). Fixed-max softmax p=exp(s-8): no shuffles/rescale in
// loop; partial (O,l) over key-halves combined once via LDS at the end.
__global__ __launch_bounds__(512) void flash_attn(
    const _Float16* __restrict__ Qd, const _Float16* __restrict__ Kd,
    const _Float16* __restrict__ Vtd,
    const float* __restrict__ wout, const float* __restrict__ bout,
    float* __restrict__ out)
{
  int j  = blockIdx.x & 15;
  int bh = blockIdx.x >> 4;
  int wave = threadIdx.x >> 6;
  int lane = threadIdx.x & 63;
  int lm = lane & 15, lq = lane >> 4;
  int g = wave >> 1;
  int h = wave & 1;

  __shared__ __align__(16) _Float16 Kl[64 * 136];   // pitch 136: 8/bank b128
  __shared__ __align__(16) _Float16 Vl[64 * 72];    // [dv][key], pitch 72
  __shared__ __align__(16) _Float16 Pl[8][16 * 40]; // per-wave P, pitch 40

  const _Float16* Kb = Kd + (size_t)bh * SS * DQK;
  const _Float16* Vb = Vtd + (size_t)bh * DH * SS;

  for (int phase = 0; phase < 2; ++phase) {
    int qt = phase == 0 ? (31 - j) : j;
    int nch = qt + 1;
    int q0 = qt * 64;

    const _Float16* Qb = Qd + ((size_t)bh * SS + q0 + g * 16) * DQK;
    half8_t aq[4];
#pragma unroll
    for (int c = 0; c < 4; c++)
      aq[c] = *(const half8_t*)(Qb + lm * DQK + c * 32 + lq * 8);

    f32x4_t o[4];
#pragma unroll
    for (int nt = 0; nt < 4; nt++) o[nt] = (f32x4_t){0.f, 0.f, 0.f, 0.f};
    float l[4] = {0.f, 0.f, 0.f, 0.f};

    for (int kt = 0; kt < nch; ++kt) {
      int k0 = kt * 64;
      __syncthreads();
      // stage K: 64 keys x 128 = 1024 x 16B segs, 2/thread
#pragma unroll
      for (int i = 0; i < 2; i++) {
        int seg = threadIdx.x + i * 512;
        int key = seg >> 4;
        int fo  = (seg & 15) * 8;
        *(half8_t*)(&Kl[key * 136 + fo]) =
            *(const half8_t*)(Kb + (size_t)(k0 + key) * DQK + fo);
      }
      {  // stage V: 64 dv x 64 keys = 512 x 16B segs, 1/thread
        int dv = threadIdx.x >> 3;
        int ko = (threadIdx.x & 7) * 8;
        *(half8_t*)(&Vl[dv * 72 + ko]) =
            *(const half8_t*)(Vb + (size_t)dv * SS + k0 + ko);
      }
      __syncthreads();

      // S = Q K^T over this wave's 32-key half: 2 tiles of 16 keys
      f32x4_t c0 = (f32x4_t){0.f, 0.f, 0.f, 0.f};
      f32x4_t c1 = (f32x4_t){0.f, 0.f, 0.f, 0.f};
#pragma unroll
      for (int c = 0; c < 4; c++) {
        half8_t b0 = *(const half8_t*)(&Kl[(h * 32 + lm) * 136 + c * 32 + lq * 8]);
        half8_t b1 = *(const half8_t*)(&Kl[(h * 32 + 16 + lm) * 136 + c * 32 + lq * 8]);
        c0 = __builtin_amdgcn_mfma_f32_16x16x32_f16(aq[c], b0, c0, 0, 0, 0);
        c1 = __builtin_amdgcn_mfma_f32_16x16x32_f16(aq[c], b1, c1, 0, 0, 0);
      }

      bool maskit = (kt == nch - 1);
      float p0[4], p1[4];
#pragma unroll
      for (int r = 0; r < 4; r++) {
        float s0 = c0[r] - 8.f;
        float s1 = c1[r] - 8.f;
        if (maskit) {
          int qrow = q0 + g * 16 + lq * 4 + r;
          if (k0 + h * 32 + lm > qrow)      s0 = -1e30f;
          if (k0 + h * 32 + 16 + lm > qrow) s1 = -1e30f;
        }
        p0[r] = __expf(s0);
        p1[r] = __expf(s1);
        l[r] += p0[r] + p1[r];
      }

      // P: C-layout -> A-layout via per-wave LDS (pitch 40)
      _Float16* pw = &Pl[wave][0];
#pragma unroll
      for (int r = 0; r < 4; r++) {
        pw[(lq * 4 + r) * 40 + lm]      = (_Float16)p0[r];
        pw[(lq * 4 + r) * 40 + 16 + lm] = (_Float16)p1[r];
      }
      half8_t pa = *(const half8_t*)(&pw[lm * 40 + lq * 8]);

#pragma unroll
      for (int nt = 0; nt < 4; nt++) {
        half8_t bv2 = *(const half8_t*)(&Vl[(nt * 16 + lm) * 72 + h * 32 + lq * 8]);
        o[nt] = __builtin_amdgcn_mfma_f32_16x16x32_f16(pa, bv2, o[nt], 0, 0, 0);
      }
    }

    // combine key-half partials: odd wave -> LDS, even wave adds + epilogue
    float* Os = (float*)&Kl[0];   // (g*64+lane)*17 + idx, 4352 f32 = fits Kl
    float* Ls = (float*)&Vl[0];   // (g*64+lane)*5 + r
    __syncthreads();
    if (h == 1) {
      float* dst = Os + ((size_t)g * 64 + lane) * 17;
#pragma unroll
      for (int nt = 0; nt < 4; nt++)
#pragma unroll
        for (int r = 0; r < 4; r++) dst[nt * 4 + r] = o[nt][r];
      float* dl = Ls + ((size_t)g * 64 + lane) * 5;
#pragma unroll
      for (int r = 0; r < 4; r++) dl[r] = l[r];
    }
    __syncthreads();
    if (h == 0) {
      const float* src = Os + ((size_t)g * 64 + lane) * 17;
#pragma unroll
      for (int nt = 0; nt < 4; nt++)
#pragma unroll
        for (int r = 0; r < 4; r++) o[nt][r] += src[nt * 4 + r];
      const float* sl = Ls + ((size_t)g * 64 + lane) * 5;
#pragma unroll
      for (int r = 0; r < 4; r++) l[r] += sl[r];
#pragma unroll
      for (int off = 1; off < 16; off <<= 1)
#pragma unroll
        for (int r = 0; r < 4; r++) l[r] += __shfl_xor(l[r], off);

      int b = bh >> 4, hh = bh & 15;
#pragma unroll
      for (int r = 0; r < 4; r++) {
        float rl = 1.f / l[r];
        int qrow = q0 + g * 16 + lq * 4 + r;
#pragma unroll
        for (int nt = 0; nt < 4; nt++) {
          int dcol = hh * DH + nt * 16 + lm;
          float ov = o[nt][r] * rl;
          float th = ov / (1.f + fabsf(wout[dcol])) + bout[dcol];
          float sn, cs; fsincos(th, &sn, &cs);
          out[((size_t)b * SS + qrow) * DD + dcol] = cs + sn;
        }
      }
    }
    // next phase's first __syncthreads (kt=0) protects Kl/Vl reuse
  }
}

extern "C" void kernel_launch(void* const* d_in, const int* in_sizes, int n_in,
                              void* d_out, int out_size, void* d_ws, size_t ws_size,
                              hipStream_t stream) {
  (void)in_sizes; (void)n_in; (void)out_size; (void)ws_size;
  const float* x   = (const float*)d_in[0];
  const float* wq  = (const float*)d_in[1];
  const float* bq  = (const float*)d_in[2];
  const float* phq = (const float*)d_in[3];
  const float* wk  = (const float*)d_in[4];
  const float* bk  = (const float*)d_in[5];
  const float* phk = (const float*)d_in[6];
  const float* wv  = (const float*)d_in[7];
  const float* bv  = (const float*)d_in[8];
  const float* wo  = (const float*)d_in[9];
  const float* bo  = (const float*)d_in[10];

  _Float16* Qd  = (_Float16*)d_ws;
  _Float16* Kd  = Qd + (size_t)BB * HH * SS * DQK;
  _Float16* Vtd = Kd + (size_t)BB * HH * SS * DQK;

  gen_qkv<<<BB * HH * (SS / 64), 256, 0, stream>>>(
      x, wq, bq, phq, wk, bk, phk, wv, bv, Qd, Kd, Vtd);
  flash_attn<<<BB * HH * 16, 512, 0, stream>>>(
      Qd, Kd, Vtd, wo, bo, (float*)d_out);
}